// Round 3
// baseline (299.475 us; speedup 1.0000x reference)
//
#include <hip/hip_runtime.h>

// Q6ArithmeticLayer: out = softmax(-hs * 3*(1 - dot(normalize(tanh(x@W^T)), normalize(P))))
// x: (32768, 1024) fp32 -> 134 MB stream (roofline ~20 us @ 6.8 TB/s measured fill BW).
// R5 == R4 resubmit (broker timeout; R4 never measured).
// R4: cross the VGPR=128 occupancy step (waves/SIMD quantize 8/4/2 at 64/128/256).
//   R2/R3 both ~150+ VGPR -> 2 waves/SIMD; that's why LDS-W alone was neutral.
//   - half-wave decomposition: each 32-lane half owns 2 tokens; lane covers 32
//     cols/token -> acc[2][6]=12 VGPR (was 24), xv[2][8]=64 (16 loads in flight).
//   - W in LDS (24 KB), 6 float4 re-read per j-chunk (48 ds_read_b128/iter;
//     49 KB LDS per 16 KB HBM = ~30% of LDS BW ceiling -- safe).
//   - reduction: xor16 token reduce-scatter (6 shfl) + xor{8,4,2,1} butterfly
//     (24 shfl) = 30 shfl / 4 tokens, 5 serial stages (was 42 / 6 stages).
//   - __launch_bounds__(256,4): cap 128 VGPR -> 16 waves/CU (2x occupancy).
//   - blocks=1024 = exactly 4 resident blocks/CU, 2 iters/wave, no churn/tail.

#define DIM 1024
#define NK 6
#define NPROTO 8
#define TPI 4  // tokens per wave iteration (2 per 32-lane half)

__global__ __launch_bounds__(256, 4) void q6_fused_kernel(
    const float* __restrict__ x,
    const float* __restrict__ W,
    const float* __restrict__ protos,
    const float* __restrict__ hs_ptr,
    float* __restrict__ out,
    int n_tokens, int n_waves)
{
    const int tid  = threadIdx.x;
    const int lane = tid & 63;
    const int wave_id = blockIdx.x * (blockDim.x >> 6) + (tid >> 6);
    const int h   = lane >> 5;    // which half: owns tokens {2h, 2h+1}
    const int sub = lane & 31;    // sub-lane within half (32 cols/token each)

    // --- stage W into LDS once per block: 6 x 1024 fp32 = 24 KB, straight copy ---
    __shared__ float4 wlds[NK * (DIM / 4)];   // wlds[k*256 + c] = W[k][4c..4c+3]
#pragma unroll
    for (int i = 0; i < (NK * DIM / 4) / 256; ++i)   // 6 iterations
        wlds[i * 256 + tid] = reinterpret_cast<const float4*>(W)[i * 256 + tid];

    // --- normalized prototype for this lane's proto slot (while W stage in flight) ---
    const int pl = lane & 7;
    float p[NK];
#pragma unroll
    for (int k = 0; k < NK; ++k) p[k] = protos[pl * NK + k];
    {
        float pn = sqrtf(p[0]*p[0] + p[1]*p[1] + p[2]*p[2] + p[3]*p[3] + p[4]*p[4] + p[5]*p[5]);
        float inv = 1.0f / fmaxf(pn, 1e-12f);
#pragma unroll
        for (int k = 0; k < NK; ++k) p[k] *= inv;
    }
    const float hs = hs_ptr[0];

    __syncthreads();

    const bool hi4 = (lane & 16) != 0;
    const int tloc = lane >> 4;   // 16-lane group g ends up owning token tb+g
    const int pidx = lane & 15;   // proto slot within the group (active if <8)

    for (int tb = wave_id * TPI; tb < n_tokens; tb += n_waves * TPI) {
        // ---- load x for this half's 2 tokens: 16 x global_load_dwordx4 in flight ----
        // lane covers cols [sub*4 + j*128 .. +3], j = 0..7, for rows tb+2h, tb+2h+1
        const float* xt = x + (size_t)(tb + 2 * h) * DIM + sub * 4;
        float4 xv[2][8];
#pragma unroll
        for (int j = 0; j < 8; ++j) xv[0][j] = *reinterpret_cast<const float4*>(&xt[j * 128]);
#pragma unroll
        for (int j = 0; j < 8; ++j) xv[1][j] = *reinterpret_cast<const float4*>(&xt[DIM + j * 128]);

        // ---- acc[t][k]: partial dots over this lane's 32 cols per token ----
        float acc[2][NK];
#pragma unroll
        for (int t = 0; t < 2; ++t)
#pragma unroll
            for (int k = 0; k < NK; ++k) acc[t][k] = 0.0f;

#pragma unroll
        for (int j = 0; j < 8; ++j) {
            float4 wk[NK];
#pragma unroll
            for (int k = 0; k < NK; ++k)
                wk[k] = wlds[k * 256 + j * 32 + sub];   // 2-way broadcast across halves
#pragma unroll
            for (int t = 0; t < 2; ++t) {
                const float4 xvj = xv[t][j];
#pragma unroll
                for (int k = 0; k < NK; ++k) {
                    float a = acc[t][k];
                    a = fmaf(xvj.x, wk[k].x, a);
                    a = fmaf(xvj.y, wk[k].y, a);
                    a = fmaf(xvj.z, wk[k].z, a);
                    a = fmaf(xvj.w, wk[k].w, a);
                    acc[t][k] = a;
                }
            }
        }

        // ---- step 1: xor16 — token reduce-scatter within each half (6 shfl) ----
        // after: 16-lane group g = lane>>4 owns token tb+g (g = 2h + (bit4))
        float z[NK];
#pragma unroll
        for (int k = 0; k < NK; ++k) {
            float send = hi4 ? acc[0][k] : acc[1][k];
            float keep = hi4 ? acc[1][k] : acc[0][k];
            z[k] = keep + __shfl_xor(send, 16, 64);
        }

        // ---- steps 2-5: butterfly within the 16-lane group (24 shfl) ----
#pragma unroll
        for (int off = 8; off >= 1; off >>= 1)
#pragma unroll
            for (int k = 0; k < NK; ++k)
                z[k] += __shfl_xor(z[k], off, 64);

        // ---- epilogue: lanes p<8 of each group handle proto p of token tloc ----
        if (pidx < NPROTO) {
            float zz[NK];
            float nrm2 = 0.0f;
#pragma unroll
            for (int k = 0; k < NK; ++k) {
                float a = z[k];
                // tanh(a) = sign(a) * (1-e)/(1+e), e = exp(-2|a|) — hw v_exp_f32
                float e = __expf(-2.0f * fabsf(a));
                float th = (1.0f - e) / (1.0f + e);
                zz[k] = copysignf(th, a);
                nrm2 = fmaf(zz[k], zz[k], nrm2);
            }
            float inv = 1.0f / fmaxf(sqrtf(nrm2), 1e-6f);
            float dot = (zz[0]*p[0] + zz[1]*p[1] + zz[2]*p[2] +
                         zz[3]*p[3] + zz[4]*p[4] + zz[5]*p[5]) * inv;
            float logit = -hs * (6.0f - dot * 6.0f) * 0.5f;
            // softmax over the 8 proto lanes (xor 1,2,4 stays in the subgroup)
            float m = logit;
            m = fmaxf(m, __shfl_xor(m, 1, 64));
            m = fmaxf(m, __shfl_xor(m, 2, 64));
            m = fmaxf(m, __shfl_xor(m, 4, 64));
            float e = __expf(logit - m);
            float s = e;
            s += __shfl_xor(s, 1, 64);
            s += __shfl_xor(s, 2, 64);
            s += __shfl_xor(s, 4, 64);
            out[(size_t)(tb + tloc) * NPROTO + pidx] = e / s;
        }
    }
}

extern "C" void kernel_launch(void* const* d_in, const int* in_sizes, int n_in,
                              void* d_out, int out_size, void* d_ws, size_t ws_size,
                              hipStream_t stream) {
    const float* x      = (const float*)d_in[0];
    const float* W      = (const float*)d_in[1];
    const float* protos = (const float*)d_in[2];
    const float* hs     = (const float*)d_in[3];
    float* out = (float*)d_out;

    const int n_tokens = in_sizes[0] / DIM;   // 32768
    const int blocks = 1024;                  // 4 blocks/CU resident, 2 iters/wave
    const int threads = 256;
    const int n_waves = blocks * (threads / 64);

    q6_fused_kernel<<<blocks, threads, 0, stream>>>(
        x, W, protos, hs, out, n_tokens, n_waves);
}